// Round 4
// baseline (1401.422 us; speedup 1.0000x reference)
//
#include <hip/hip_runtime.h>
#include <hip/hip_bf16.h>
#include <stdint.h>
#include <string.h>

#define HIDDEN 1024
#define FEAT   512
#define PREV   10
#define PRED   20
#define BATCH  1024
#define KTOT   (HIDDEN + FEAT)   // 1536
#define N4H    4096
#define TSTEPS (PREV + PRED)     // 30
#define NBLK   256               // 1 block/CU on 256 CUs
#define NTHR   512
#define NKT    24                // KTOT/64 k-tiles
#define TILEB  16384             // per-buffer LDS: 128 rows x 128 B

typedef __attribute__((ext_vector_type(8))) short short8;
typedef __attribute__((ext_vector_type(4))) float f32x4;
typedef unsigned long long ull;

// ---- async global->LDS 16B copy (wave-uniform LDS base + lane*16), plain-cached ----
typedef __attribute__((address_space(3))) unsigned int u32_lds;
typedef const __attribute__((address_space(1))) unsigned int u32_gbl;

__device__ __forceinline__ void async16(void* lds, const void* g) {
  u32_lds* lp = (u32_lds*)(unsigned int)(uintptr_t)lds;
  u32_gbl* gp = (u32_gbl*)(uintptr_t)g;
  __builtin_amdgcn_global_load_lds(gp, lp, 16, 0, 0);
}

__device__ __forceinline__ float sigmoidf_(float x) {
  return 1.0f / (1.0f + __expf(-x));
}
__device__ __forceinline__ float tanhf_(float x) {
  return 1.0f - 2.0f / (1.0f + __expf(2.0f * x));
}

// device-coherent (LLC) accesses — bypass the non-coherent L1/L2. Compiler-visible:
// waits and spills are handled by codegen (no asm loads anywhere in this kernel).
__device__ __forceinline__ ull cload(const void* p) {
  return __hip_atomic_load((const ull*)p, __ATOMIC_RELAXED, __HIP_MEMORY_SCOPE_AGENT);
}
__device__ __forceinline__ void cstore(void* p, ull v) {
  __hip_atomic_store((ull*)p, v, __ATOMIC_RELAXED, __HIP_MEMORY_SCOPE_AGENT);
}
__device__ __forceinline__ float cload4(const void* p) {
  return __hip_atomic_load((const float*)p, __ATOMIC_RELAXED, __HIP_MEMORY_SCOPE_AGENT);
}
__device__ __forceinline__ void cstore4(void* p, float v) {
  __hip_atomic_store((float*)p, v, __ATOMIC_RELAXED, __HIP_MEMORY_SCOPE_AGENT);
}

// ---- pack [Wh;Wx] (fp32, [K,4096] gate-blocked) -> WpT (bf16, [4096,K], gate-interleaved n=4j+g) ----
__global__ void pack_w_kernel(const float* __restrict__ Wx, const float* __restrict__ Wh,
                              __hip_bfloat16* __restrict__ WpT) {
  __shared__ float tile[64][65];
  const int k0 = blockIdx.x * 64, n0 = blockIdx.y * 64;
  const int tid = threadIdx.x;
  const float* src = (k0 < HIDDEN) ? (Wh + (size_t)k0 * N4H) : (Wx + (size_t)(k0 - HIDDEN) * N4H);
  {
    const int jl = tid & 15, g = (tid >> 4) & 3, klb = tid >> 6;
#pragma unroll
    for (int it = 0; it < 16; ++it) {
      int kl = klb + it * 4;
      tile[kl][4 * jl + g] = src[(size_t)kl * N4H + g * HIDDEN + (n0 >> 2) + jl];
    }
  }
  __syncthreads();
  {
    const int kl = tid & 63, nlb = tid >> 6;
#pragma unroll
    for (int it = 0; it < 16; ++it) {
      int nl = nlb + it * 4;
      WpT[(size_t)(n0 + nl) * KTOT + k0 + kl] = __float2bfloat16(tile[kl][nl]);
    }
  }
}

// ---- re-layout WpT -> Wf, MFMA-fragment-major: frag(ng,kg) = 1KB, lane l holds
// W[n = ng*16 + (l&15)][k = kg*32 + (l>>4)*8 .. +8]. Coalesced 16B/lane reads in the LSTM. ----
__global__ void pack_wf_kernel(const __hip_bfloat16* __restrict__ WpT,
                               __hip_bfloat16* __restrict__ Wf) {
  int id = blockIdx.x * 256 + threadIdx.x;   // (N4H/16)*(KTOT/32)*64 = 786432
  if (id >= (N4H / 16) * (KTOT / 32) * 64) return;
  int l = id & 63, fg = id >> 6;
  int kg = fg % (KTOT / 32), ng = fg / (KTOT / 32);
  int n = ng * 16 + (l & 15);
  int k0 = kg * 32 + (l >> 4) * 8;
  *(short8*)(Wf + (size_t)id * 8) = *(const short8*)(WpT + (size_t)n * KTOT + k0);
}

__global__ void pack_bias_kernel(const float* __restrict__ b, float* __restrict__ bp) {
  int n = blockIdx.x * 256 + threadIdx.x;
  if (n < N4H) bp[n] = b[(n & 3) * HIDDEN + (n >> 2)];
}

// ---- convert inputs fp32 -> bf16 ----
__global__ void cvt_x_kernel(const float* __restrict__ xr, const float* __restrict__ xf,
                             __hip_bfloat16* __restrict__ xrb, __hip_bfloat16* __restrict__ xfb) {
  const int NR4 = BATCH * TSTEPS * FEAT / 4;
  const int NF4 = BATCH * PRED * FEAT / 4;
  int i = blockIdx.x * 256 + threadIdx.x;
  float4 v;
  __hip_bfloat16* dst;
  if (i < NR4) {
    v = ((const float4*)xr)[i];
    dst = xrb + (size_t)i * 4;
  } else {
    int j = i - NR4;
    if (j >= NF4) return;
    v = ((const float4*)xf)[j];
    dst = xfb + (size_t)j * 4;
  }
  dst[0] = __float2bfloat16(v.x);
  dst[1] = __float2bfloat16(v.y);
  dst[2] = __float2bfloat16(v.z);
  dst[3] = __float2bfloat16(v.w);
}

// ---- persistent LSTM ----
// 256 blocks x 512 thr, 1 block/CU. Operand-SWAPPED GEMM: z = W·h, D[n][batch].
// Block tile [n=256][batch=128]; 8 waves = 4(wn) x 2(wb), each 64x64.
// W (A-operand): fragment-major Wf, PLAIN compiler loads into double-slot
// registers (wSA/wSB via 2-body unroll). h/x (B-operand): double-buffered LDS
// (16 KB/buf); h via compiler-visible LLC-coherent 8B atomic loads -> ds_write,
// x via global_load_lds. ONE __syncthreads per k-tile body: its built-in
// vmcnt(0)/lgkmcnt(0) drain is the only wait discipline — no manual s_waitcnt,
// so correctness is independent of register allocation/spills. Overlap comes
// from issue order: stage(KT+1)+W(KT+1) issued before compute(KT); the h
// deposit (ds_write) lands after compute. Gates fully in registers
// (acc quad = i,f,g,o of one j); cell state in registers.
__global__ __launch_bounds__(512, 2)
void lstm_persistent(const __hip_bfloat16* __restrict__ xrb,
                     const __hip_bfloat16* __restrict__ xfb,
                     const __hip_bfloat16* __restrict__ Wf,
                     const float* __restrict__ biasp,
                     const float* __restrict__ w2,
                     __hip_bfloat16* __restrict__ hb0,
                     __hip_bfloat16* __restrict__ hb1,
                     float* __restrict__ cbuf,
                     float* __restrict__ accout,
                     unsigned* __restrict__ bar) {
  __shared__ __align__(16) char smem[2 * TILEB + 128 * 68 * 2];  // 32K stage + 17K h-pack

  const int tid = threadIdx.x;
  const int bid = blockIdx.x;
  const int nt = bid & 15, rt = bid >> 4;   // bid%8 -> XCD; W slice 2x786KB L2-resident
  const int n0 = nt * 256;
  const int r0 = rt * 128;
  const int w = tid >> 6, l = tid & 63;
  const int sub = l >> 3;
  const int csrc = (l & 7) ^ sub;           // XOR-swizzled 16B source chunk
  const int quad = l >> 4, lrow = l & 15;
  const int wn = w & 3, wb = w >> 2;        // wave: n-range wn*64, batch-range wb*64
  unsigned* cnt = bar;
  unsigned* flag = bar + 32;
  unsigned short* hT = (unsigned short*)(smem + 2 * TILEB);

  // per-lane W fragment base: frags for ng = nt*16 + wn*4 + mi, kg = 2*kt + kk
  const char* wfL = (const char*)Wf + ((size_t)(nt * 16 + wn * 4) * (KTOT / 32)) * 1024 + (size_t)l * 16;
  const int ldsW = (w * 16 + sub) * 128 + (l & 7) * 16;  // h deposit (matches async16 layout)

  // hoisted per-lane w2 (j = nt*64 + wn*16 + mi*4 + quad)
  float w2r[4];
#pragma unroll
  for (int mi = 0; mi < 4; ++mi) w2r[mi] = w2[nt * 64 + wn * 16 + mi * 4 + quad];

  float creg[16];
#pragma unroll
  for (int i = 0; i < 16; ++i) creg[i] = 0.f;

  short8 wSA[8], wSB[8];
  ull sd0, sd1, sd2, sd3;

// ---- W fragments for k-tile S -> register slot WS (8 plain coalesced 16B loads) ----
#define ISSUE_W(S, WS)                                                                 \
  do {                                                                                 \
    if ((S) < NKT) {                                                                   \
      const char* _wp = wfL + (size_t)(S) * 2048;                                      \
      _Pragma("unroll")                                                                \
      for (int _mi = 0; _mi < 4; ++_mi)                                                \
        _Pragma("unroll")                                                              \
        for (int _kk = 0; _kk < 2; ++_kk)                                              \
          WS[_mi * 2 + _kk] =                                                          \
              *(const short8*)(_wp + _mi * ((KTOT / 32) * 1024) + _kk * 1024);         \
    }                                                                                  \
  } while (0)

// ---- stage h/x k-tile S: h-range -> regs (4x8B coherent loads); x-range -> async16 ----
#define STAGE_ISSUE(S)                                                                 \
  do {                                                                                 \
    if ((S) < 16) {                                                                    \
      sd0 = cload(hsA0 + (size_t)(S) * 64);                                            \
      sd1 = cload(hsA0 + (size_t)(S) * 64 + 4);                                        \
      sd2 = cload(hsA1 + (size_t)(S) * 64);                                            \
      sd3 = cload(hsA1 + (size_t)(S) * 64 + 4);                                        \
    } else if ((S) < NKT) {                                                            \
      char* _sb = smem + ((S) & 1) * TILEB;                                            \
      async16(_sb + (w * 16) * 128,     xA0 + (size_t)((S) * 64 - HIDDEN));            \
      async16(_sb + (w * 16 + 8) * 128, xA1 + (size_t)((S) * 64 - HIDDEN));            \
    }                                                                                  \
  } while (0)

#define STAGE_WRITE(S)                                                                 \
  do {                                                                                 \
    if ((S) < 16) {                                                                    \
      ull* _lw = (ull*)(smem + ((S) & 1) * TILEB + ldsW);                              \
      _lw[0] = sd0;                                                                    \
      _lw[1] = sd1;                                                                    \
      ull* _lw2 = (ull*)(smem + ((S) & 1) * TILEB + ldsW + 1024);                      \
      _lw2[0] = sd2;                                                                   \
      _lw2[1] = sd3;                                                                   \
    }                                                                                  \
  } while (0)

#define KT_COMPUTE(KT, WS)                                                             \
  do {                                                                                 \
    const char* _cb = smem + ((KT) & 1) * TILEB;                                       \
    _Pragma("unroll")                                                                  \
    for (int kk = 0; kk < 2; ++kk) {                                                   \
      const int swz = (((kk << 2) + quad) ^ (lrow & 7)) * 16;                          \
      short8 bf[4];                                                                    \
      _Pragma("unroll")                                                                \
      for (int bi = 0; bi < 4; ++bi)                                                   \
        bf[bi] = *(const short8*)(_cb + (wb * 64 + bi * 16 + lrow) * 128 + swz);       \
      _Pragma("unroll")                                                                \
      for (int mi = 0; mi < 4; ++mi)                                                   \
        _Pragma("unroll")                                                              \
        for (int bi = 0; bi < 4; ++bi)                                                 \
          acc[mi][bi] = __builtin_amdgcn_mfma_f32_16x16x32_bf16(WS[mi * 2 + kk],       \
                            bf[bi], acc[mi][bi], 0, 0, 0);                             \
    }                                                                                  \
  } while (0)

// one 64-k tile: issue stage(KT+1) + W(KT+1) loads; compute(KT) from cur buffer +
// cur W slot; deposit h(KT+1) into the other buffer; single barrier (drains all).
#define KT_BODY(KT, WSc, WSn)                                                          \
  do {                                                                                 \
    STAGE_ISSUE((KT) + 1);                                                             \
    ISSUE_W((KT) + 1, WSn);                                                            \
    KT_COMPUTE(KT, WSc);                                                               \
    STAGE_WRITE((KT) + 1);                                                             \
    __syncthreads();                                                                   \
  } while (0)

#pragma unroll 1
  for (int t = 0; t < TSTEPS; ++t) {
    const unsigned short* hcur = (const unsigned short*)((t & 1) ? hb1 : hb0);
    unsigned short* hnx = (unsigned short*)((t & 1) ? hb0 : hb1);
    const bool active = (t >= PREV) || (rt < 8);

    if (active) {
      if (t == PREV && r0 >= BATCH) {
        // fork: pick up cell state written at t==9 by real-row owners (LLC-coherent)
#pragma unroll
        for (int mi = 0; mi < 4; ++mi)
#pragma unroll
          for (int bi = 0; bi < 4; ++bi)
            creg[mi * 4 + bi] = cload4(&cbuf[(size_t)(r0 - BATCH + wb * 64 + bi * 16 + lrow) * HIDDEN
                                             + nt * 64 + wn * 16 + mi * 4 + quad]);
      }
      const int r0h = (t == PREV && r0 >= BATCH) ? (r0 - BATCH) : r0;

      const unsigned short* hsA0 = hcur + (size_t)(r0h + w * 16 + sub) * HIDDEN + csrc * 8;
      const unsigned short* hsA1 = hsA0 + 8 * HIDDEN;
      const unsigned short* xb;
      size_t xstr;
      if (r0 < BATCH) {
        xb = (const unsigned short*)xrb + ((size_t)r0 * TSTEPS + t) * FEAT;
        xstr = (size_t)TSTEPS * FEAT;
      } else {
        xb = (const unsigned short*)xfb + ((size_t)(r0 - BATCH) * PRED + (t - PREV)) * FEAT;
        xstr = (size_t)PRED * FEAT;
      }
      const unsigned short* xA0 = xb + (w * 16 + sub) * xstr + csrc * 8;
      const unsigned short* xA1 = xA0 + 8 * xstr;

      f32x4 acc[4][4];
#pragma unroll
      for (int a = 0; a < 4; ++a)
#pragma unroll
        for (int b_ = 0; b_ < 4; ++b_) acc[a][b_] = (f32x4){0.f, 0.f, 0.f, 0.f};

      // prologue: tile 0 staged + deposited; W(0) loaded (t>0: prefetched pre-barrier)
      STAGE_ISSUE(0);
      if (t == 0) ISSUE_W(0, wSA);
      STAGE_WRITE(0);
      __syncthreads();

#pragma unroll 1
      for (int m2 = 0; m2 < NKT / 2; ++m2) {
        const int kt = 2 * m2;
        KT_BODY(kt, wSA, wSB);
        KT_BODY(kt + 1, wSB, wSA);
      }

      // ---- epilogue: gates fully in registers (acc quad = i,f,g,o of one j) ----
      const int kout = t - PREV;
      float psum[4] = {0.f, 0.f, 0.f, 0.f};
#pragma unroll
      for (int mi = 0; mi < 4; ++mi) {
        const float4 bi4 = *(const float4*)&biasp[n0 + wn * 64 + mi * 16 + quad * 4];
#pragma unroll
        for (int bi = 0; bi < 4; ++bi) {
          f32x4 z = acc[mi][bi];
          float gi = sigmoidf_(z[0] + bi4.x);
          float gf = sigmoidf_(z[1] + bi4.y);
          float gg = tanhf_(z[2] + bi4.z);
          float go = sigmoidf_(z[3] + bi4.w);
          const int ci = mi * 4 + bi;
          float cnew = gf * creg[ci] + gi * gg;
          float hnew = go * tanhf_(cnew);
          creg[ci] = cnew;
          __hip_bfloat16 hbv = __float2bfloat16(hnew);
          hT[(wb * 64 + bi * 16 + lrow) * 68 + wn * 16 + mi * 4 + quad] =
              *(unsigned short*)&hbv;
          if (t >= PREV) psum[bi] += hnew * w2r[mi];
          if (t == PREV - 1)
            cstore4(&cbuf[(size_t)(r0 + wb * 64 + bi * 16 + lrow) * HIDDEN
                          + nt * 64 + wn * 16 + mi * 4 + quad], cnew);
        }
      }
      __syncthreads();
      // pack & store h: 128 rows x 64 j, 8B coherent stores
      {
        const int er = tid >> 2, ejq = tid & 3;
#pragma unroll
        for (int it = 0; it < 4; ++it) {
          int jl = ejq * 16 + it * 4;
          ull v;
          memcpy(&v, &hT[er * 68 + jl], 8);
          cstore(hnx + (size_t)(r0 + er) * HIDDEN + nt * 64 + jl, v);
        }
      }
      if (t >= PREV) {
#pragma unroll
        for (int bi = 0; bi < 4; ++bi) {
          float v = psum[bi];
          v += __shfl_down(v, 32);
          v += __shfl_down(v, 16);
          if (quad == 0)
            atomicAdd(&accout[(size_t)(r0 + wb * 64 + bi * 16 + lrow) * PRED + kout], v);
        }
      }
    }

    // ---- grid barrier (LLC atomics). __syncthreads' vmcnt(0)/lgkmcnt(0) drain
    // puts h/c stores at the LLC before the signal. W(0) prefetch rides the drain.
    if (t < TSTEPS - 1) {
      const bool nact = (t + 1 >= PREV) || (rt < 8);
      if (nact) ISSUE_W(0, wSA);
      __syncthreads();
      if (tid == 0) {
        unsigned ph = (unsigned)(t + 1);
        unsigned old = __hip_atomic_fetch_add(cnt, 1u, __ATOMIC_RELAXED, __HIP_MEMORY_SCOPE_AGENT);
        if (old == NBLK - 1) {
          __hip_atomic_store(cnt, 0u, __ATOMIC_RELAXED, __HIP_MEMORY_SCOPE_AGENT);
          __hip_atomic_store(flag, ph, __ATOMIC_RELAXED, __HIP_MEMORY_SCOPE_AGENT);
        } else {
          while (__hip_atomic_load(flag, __ATOMIC_RELAXED, __HIP_MEMORY_SCOPE_AGENT) < ph)
            __builtin_amdgcn_s_sleep(4);
        }
      }
      __syncthreads();
    }
  }
#undef ISSUE_W
#undef STAGE_ISSUE
#undef STAGE_WRITE
#undef KT_COMPUTE
#undef KT_BODY
}

// ---- final tanh chain over the 40960 fused dots ----
__global__ void final_kernel(const float* __restrict__ accout, const float* __restrict__ b2,
                             const float* __restrict__ w3, const float* __restrict__ b3,
                             const float* __restrict__ w4, const float* __restrict__ b4,
                             float* __restrict__ out) {
  int i = blockIdx.x * 256 + threadIdx.x;
  const int half = BATCH * PRED;
  if (i >= 2 * half) return;
  int r, k;
  if (i < half) {
    r = i / PRED;
    k = i % PRED;
  } else {
    r = BATCH + (i - half) / PRED;
    k = (i - half) % PRED;
  }
  float x = tanhf_(accout[r * PRED + k] + b2[0]);
  x = tanhf_(x * w3[0] + b3[0]);
  x = tanhf_(x * w4[0] + b4[0]);
  out[i] = x;
}

extern "C" void kernel_launch(void* const* d_in, const int* in_sizes, int n_in,
                              void* d_out, int out_size, void* d_ws, size_t ws_size,
                              hipStream_t stream) {
  const float* real_input = (const float*)d_in[0];
  const float* fake_input = (const float*)d_in[1];
  const float* Wx = (const float*)d_in[2];
  const float* Wh = (const float*)d_in[3];
  const float* b  = (const float*)d_in[4];
  const float* w2 = (const float*)d_in[5];
  const float* b2 = (const float*)d_in[6];
  const float* w3 = (const float*)d_in[7];
  const float* b3 = (const float*)d_in[8];
  const float* w4 = (const float*)d_in[9];
  const float* b4 = (const float*)d_in[10];
  float* out = (float*)d_out;

  char* ws = (char*)d_ws;
  size_t off = 0;
  __hip_bfloat16* Wf = (__hip_bfloat16*)(ws + off);   off += (size_t)N4H * KTOT * 2;
  float* biasp = (float*)(ws + off);                  off += (size_t)N4H * 4;
  __hip_bfloat16* hb0 = (__hip_bfloat16*)(ws + off);  off += (size_t)2 * BATCH * HIDDEN * 2;
  __hip_bfloat16* hb1 = (__hip_bfloat16*)(ws + off);  off += (size_t)2 * BATCH * HIDDEN * 2;
  float* cbuf = (float*)(ws + off);                   off += (size_t)BATCH * HIDDEN * 4;
  float* accout = (float*)(ws + off);                 off += (size_t)2 * BATCH * PRED * 4;
  unsigned* bar = (unsigned*)(ws + off);              off += 256;
  // transient region: WpT (pack intermediate) aliases xrb (WpT dead before cvt_x runs)
  __hip_bfloat16* xrb = (__hip_bfloat16*)(ws + off);
  __hip_bfloat16* WpT = (__hip_bfloat16*)(ws + off);  off += (size_t)BATCH * TSTEPS * FEAT * 2;
  __hip_bfloat16* xfb = (__hip_bfloat16*)(ws + off);  off += (size_t)BATCH * PRED * FEAT * 2;

  hipMemsetAsync(hb0, 0, (size_t)2 * BATCH * HIDDEN * 2, stream);
  hipMemsetAsync(accout, 0, (size_t)2 * BATCH * PRED * 4, stream);
  hipMemsetAsync(bar, 0, 256, stream);

  pack_w_kernel<<<dim3(KTOT / 64, N4H / 64), 256, 0, stream>>>(Wx, Wh, WpT);
  pack_bias_kernel<<<N4H / 256, 256, 0, stream>>>(b, biasp);
  pack_wf_kernel<<<((N4H / 16) * (KTOT / 32) * 64 + 255) / 256, 256, 0, stream>>>(WpT, Wf);
  {
    int n4 = BATCH * TSTEPS * FEAT / 4 + BATCH * PRED * FEAT / 4;
    cvt_x_kernel<<<(n4 + 255) / 256, 256, 0, stream>>>(real_input, fake_input, xrb, xfb);
  }

  {
    const __hip_bfloat16* a_xrb = xrb;
    const __hip_bfloat16* a_xfb = xfb;
    const __hip_bfloat16* a_Wf = Wf;
    const float* a_biasp = biasp;
    const float* a_w2 = w2;
    __hip_bfloat16* a_hb0 = hb0;
    __hip_bfloat16* a_hb1 = hb1;
    float* a_cbuf = cbuf;
    float* a_acc = accout;
    unsigned* a_bar = bar;
    void* args[10] = {&a_xrb, &a_xfb, &a_Wf, &a_biasp, &a_w2,
                      &a_hb0, &a_hb1, &a_cbuf, &a_acc, &a_bar};
    hipError_t e = hipLaunchCooperativeKernel((const void*)lstm_persistent,
                                              dim3(NBLK), dim3(NTHR), args, 0, stream);
    if (e != hipSuccess) {
      // co-residency fallback: 256 blocks at ~49 KB LDS / <=256 VGPR are 1/CU resident
      lstm_persistent<<<dim3(NBLK), dim3(NTHR), 0, stream>>>(
          xrb, xfb, Wf, biasp, w2, hb0, hb1, cbuf, accout, bar);
    }
  }

  final_kernel<<<(2 * BATCH * PRED + 255) / 256, 256, 0, stream>>>(accout, b2, w3, b3, w4, b4, out);
}

// Round 5
// 1361.305 us; speedup vs baseline: 1.0295x; 1.0295x over previous
//
#include <hip/hip_runtime.h>
#include <hip/hip_bf16.h>
#include <stdint.h>
#include <string.h>

#define HIDDEN 1024
#define FEAT   512
#define PREV   10
#define PRED   20
#define BATCH  1024
#define KTOT   (HIDDEN + FEAT)   // 1536
#define N4H    4096
#define TSTEPS (PREV + PRED)     // 30
#define NBLK   256               // 1 block/CU on 256 CUs
#define NTHR   512
#define NKT    24                // KTOT/64 k-tiles
#define NKG    (KTOT / 32)       // 48 k-groups (32 h + 16 x)
#define STEPB  ((size_t)128 * NKG * 1024)   // 6 MB per-step B-fragment buffer

typedef __attribute__((ext_vector_type(8))) short short8;
typedef __attribute__((ext_vector_type(4))) float f32x4;
typedef unsigned long long ull;

__device__ __forceinline__ float sigmoidf_(float x) {
  return 1.0f / (1.0f + __expf(-x));
}
__device__ __forceinline__ float tanhf_(float x) {
  return 1.0f - 2.0f / (1.0f + __expf(2.0f * x));
}
__device__ __forceinline__ unsigned short f2bf(float x) {
  __hip_bfloat16 h = __float2bfloat16(x);
  unsigned short u;
  memcpy(&u, &h, 2);
  return u;
}

// device-coherent (LLC write-through) stores; agent-scope loads for fork/cell state.
// All compiler-visible (no asm): waits and spills handled by codegen.
__device__ __forceinline__ void cstore(void* p, ull v) {
  __hip_atomic_store((ull*)p, v, __ATOMIC_RELAXED, __HIP_MEMORY_SCOPE_AGENT);
}
__device__ __forceinline__ float cload4(const void* p) {
  return __hip_atomic_load((const float*)p, __ATOMIC_RELAXED, __HIP_MEMORY_SCOPE_AGENT);
}
__device__ __forceinline__ void cstore4(void* p, float v) {
  __hip_atomic_store((float*)p, v, __ATOMIC_RELAXED, __HIP_MEMORY_SCOPE_AGENT);
}

// ---- pack [Wh;Wx] (fp32, [K,4096] gate-blocked) -> WpT (bf16, [4096,K], gate-interleaved n=4j+g) ----
__global__ void pack_w_kernel(const float* __restrict__ Wx, const float* __restrict__ Wh,
                              __hip_bfloat16* __restrict__ WpT) {
  __shared__ float tile[64][65];
  const int k0 = blockIdx.x * 64, n0 = blockIdx.y * 64;
  const int tid = threadIdx.x;
  const float* src = (k0 < HIDDEN) ? (Wh + (size_t)k0 * N4H) : (Wx + (size_t)(k0 - HIDDEN) * N4H);
  {
    const int jl = tid & 15, g = (tid >> 4) & 3, klb = tid >> 6;
#pragma unroll
    for (int it = 0; it < 16; ++it) {
      int kl = klb + it * 4;
      tile[kl][4 * jl + g] = src[(size_t)kl * N4H + g * HIDDEN + (n0 >> 2) + jl];
    }
  }
  __syncthreads();
  {
    const int kl = tid & 63, nlb = tid >> 6;
#pragma unroll
    for (int it = 0; it < 16; ++it) {
      int nl = nlb + it * 4;
      WpT[(size_t)(n0 + nl) * KTOT + k0 + kl] = __float2bfloat16(tile[kl][nl]);
    }
  }
}

// ---- re-layout WpT -> Wf, MFMA-fragment-major: frag(ng,kg) = 1KB, lane l holds
// W[n = ng*16 + (l&15)][k = kg*32 + (l>>4)*8 .. +8]. Coalesced 16B/lane reads in the LSTM. ----
__global__ void pack_wf_kernel(const __hip_bfloat16* __restrict__ WpT,
                               __hip_bfloat16* __restrict__ Wf) {
  int id = blockIdx.x * 256 + threadIdx.x;   // (N4H/16)*NKG*64 = 786432
  if (id >= (N4H / 16) * NKG * 64) return;
  int l = id & 63, fg = id >> 6;
  int kg = fg % NKG, ng = fg / NKG;
  int n = ng * 16 + (l & 15);
  int k0 = kg * 32 + (l >> 4) * 8;
  *(short8*)(Wf + (size_t)id * 8) = *(const short8*)(WpT + (size_t)n * KTOT + k0);
}

__global__ void pack_bias_kernel(const float* __restrict__ b, float* __restrict__ bp) {
  int n = blockIdx.x * 256 + threadIdx.x;
  if (n < N4H) bp[n] = b[(n & 3) * HIDDEN + (n >> 2)];
}

// ---- pack x (fp32) -> bF[t] x-fragments (kg = 32..47), frag-major bf16 ----
// frag(bg, t, kgx) lane l = x[batch = bg*16+(l&15)][t][feat = kgx*32+(l>>4)*8 ..+8]
__global__ void pack_bx_kernel(const float* __restrict__ xr, const float* __restrict__ xf,
                               char* __restrict__ bF) {
  const int REALF = 64 * TSTEPS * 16;  // 30720 frags
  const int FAKEF = 64 * PRED * 16;    // 20480 frags
  int id = blockIdx.x * 256 + threadIdx.x;
  int fid = id >> 6, l = id & 63;
  if (fid >= REALF + FAKEF) return;
  const float* src;
  int bg, t, kgx;
  if (fid < REALF) {
    kgx = fid & 15;
    int r = fid >> 4;
    t = r % TSTEPS;
    bg = r / TSTEPS;
    src = xr + ((size_t)(bg * 16 + (l & 15)) * TSTEPS + t) * FEAT + kgx * 32 + (l >> 4) * 8;
  } else {
    int f2 = fid - REALF;
    kgx = f2 & 15;
    int r = f2 >> 4;
    int tf = r % PRED;
    int bg2 = r / PRED;
    t = PREV + tf;
    bg = 64 + bg2;
    src = xf + ((size_t)(bg2 * 16 + (l & 15)) * PRED + tf) * FEAT + kgx * 32 + (l >> 4) * 8;
  }
  float4 v0 = *(const float4*)src;
  float4 v1 = *(const float4*)(src + 4);
  short8 o;
  o[0] = (short)f2bf(v0.x);
  o[1] = (short)f2bf(v0.y);
  o[2] = (short)f2bf(v0.z);
  o[3] = (short)f2bf(v0.w);
  o[4] = (short)f2bf(v1.x);
  o[5] = (short)f2bf(v1.y);
  o[6] = (short)f2bf(v1.z);
  o[7] = (short)f2bf(v1.w);
  *(short8*)(bF + (size_t)t * STEPB + (((size_t)bg * NKG + 32 + kgx) << 10) + l * 16) = o;
}

// ---- persistent LSTM: BARRIER-FREE register k-loop ----
// 256 blocks x 512 thr, 1 block/CU. Operand-swapped GEMM z = W·h, D[n][batch].
// Block tile [n=256][batch=128]; 8 waves = 4(wn) x 2(wb), each 64x64 (4mi x 4bi frags).
// Both operands are MFMA fragments loaded straight from global into registers
// (A: Wf, plain loads, L2-resident slice; B: bF[t], plain loads — SAFE because
// bF buffers are per-step-unique: no address re-read, so L1/L2 can never serve
// stale data, while producers write through to LLC via agent stores). The
// 24-tile k-loop has NO LDS and NO barriers — 2-slot register double-buffer
// gives one-tile prefetch distance. LDS only for the epilogue hT transpose.
// Gates fully in registers (acc quad = i,f,g,o of one j); cell state in regs.
__global__ __launch_bounds__(512, 2)
void lstm_persistent(char* __restrict__ bF,
                     const __hip_bfloat16* __restrict__ Wf,
                     const float* __restrict__ biasp,
                     const float* __restrict__ w2,
                     float* __restrict__ cbuf,
                     float* __restrict__ accout,
                     unsigned* __restrict__ bar) {
  __shared__ __align__(16) unsigned short hT[128 * 68];  // 17 KB transpose tile

  const int tid = threadIdx.x;
  const int bid = blockIdx.x;
  const int nt = bid & 15, rt = bid >> 4;   // bid%8 -> XCD; W slice 2x786KB L2-resident
  const int n0 = nt * 256;
  const int r0 = rt * 128;
  const int w = tid >> 6, l = tid & 63;
  const int quad = l >> 4, lrow = l & 15;
  const int wn = w & 3, wb = w >> 2;        // wave: n-range wn*64, batch-range wb*64
  unsigned* cnt = bar;
  unsigned* flag = bar + 32;

  // per-lane W fragment base: frags for ng = nt*16 + wn*4 + mi, kg = 2*kt + kk
  const char* wfL = (const char*)Wf + ((size_t)(nt * 16 + wn * 4) * NKG) * 1024 + (size_t)l * 16;

  // hoisted per-lane w2 (j = nt*64 + wn*16 + mi*4 + quad)
  float w2r[4];
#pragma unroll
  for (int mi = 0; mi < 4; ++mi) w2r[mi] = w2[nt * 64 + wn * 16 + mi * 4 + quad];

  float creg[16];
#pragma unroll
  for (int i = 0; i < 16; ++i) creg[i] = 0.f;

#define LOADA(S, WS)                                                                   \
  do {                                                                                 \
    _Pragma("unroll")                                                                  \
    for (int _mi = 0; _mi < 4; ++_mi)                                                  \
      _Pragma("unroll")                                                                \
      for (int _kk = 0; _kk < 2; ++_kk)                                                \
        WS[_mi * 2 + _kk] = *(const short8*)(wfL + (size_t)_mi * (NKG * 1024) +        \
                                             (((size_t)(S) * 2 + _kk) << 10));         \
  } while (0)

#define LOADB(S, HS)                                                                   \
  do {                                                                                 \
    const char* _b = ((S) < 16) ? bLh : bLx;                                           \
    _Pragma("unroll")                                                                  \
    for (int _bi = 0; _bi < 4; ++_bi)                                                  \
      _Pragma("unroll")                                                                \
      for (int _kk = 0; _kk < 2; ++_kk)                                                \
        HS[_bi * 2 + _kk] = *(const short8*)(_b + (size_t)_bi * (NKG * 1024) +         \
                                             (((size_t)(S) * 2 + _kk) << 10));         \
  } while (0)

#define COMP(WS, HS)                                                                   \
  do {                                                                                 \
    _Pragma("unroll")                                                                  \
    for (int _kk = 0; _kk < 2; ++_kk)                                                  \
      _Pragma("unroll")                                                                \
      for (int _mi = 0; _mi < 4; ++_mi)                                                \
        _Pragma("unroll")                                                              \
        for (int _bi = 0; _bi < 4; ++_bi)                                              \
          acc[_mi][_bi] = __builtin_amdgcn_mfma_f32_16x16x32_bf16(                     \
              WS[_mi * 2 + _kk], HS[_bi * 2 + _kk], acc[_mi][_bi], 0, 0, 0);           \
  } while (0)

#pragma unroll 1
  for (int t = 0; t < TSTEPS; ++t) {
    const bool active = (t >= PREV) || (rt < 8);

    if (active) {
      if (t == PREV && r0 >= BATCH) {
        // fork: pick up cell state written at t==9 by real-row owners (LLC-coherent)
#pragma unroll
        for (int mi = 0; mi < 4; ++mi)
#pragma unroll
          for (int bi = 0; bi < 4; ++bi)
            creg[mi * 4 + bi] = cload4(&cbuf[(size_t)(r0 - BATCH + wb * 64 + bi * 16 + lrow) * HIDDEN
                                             + nt * 64 + wn * 16 + mi * 4 + quad]);
      }
      const int r0h = (t == PREV && r0 >= BATCH) ? (r0 - BATCH) : r0;

      const char* bT = bF + (size_t)t * STEPB;
      // h-frags follow the fork redirect (r0h); x-frags always use own rows (r0)
      const char* bLh = bT + (((size_t)((r0h >> 4) + wb * 4) * NKG) << 10) + (size_t)l * 16;
      const char* bLx = bT + (((size_t)((r0  >> 4) + wb * 4) * NKG) << 10) + (size_t)l * 16;

      f32x4 acc[4][4];
#pragma unroll
      for (int a = 0; a < 4; ++a)
#pragma unroll
        for (int b_ = 0; b_ < 4; ++b_) acc[a][b_] = (f32x4){0.f, 0.f, 0.f, 0.f};

      short8 wA[8], hB[8], wA2[8], hB2[8];
      LOADA(0, wA);
      LOADB(0, hB);
#pragma unroll 1
      for (int kt = 0; kt < NKT; kt += 2) {
        LOADA(kt + 1, wA2);
        LOADB(kt + 1, hB2);
        COMP(wA, hB);
        if (kt + 2 < NKT) {
          LOADA(kt + 2, wA);
          LOADB(kt + 2, hB);
        }
        COMP(wA2, hB2);
      }

      // ---- epilogue: gates fully in registers (acc quad = i,f,g,o of one j) ----
      const int kout = t - PREV;
      float psum[4] = {0.f, 0.f, 0.f, 0.f};
#pragma unroll
      for (int mi = 0; mi < 4; ++mi) {
        const float4 bi4 = *(const float4*)&biasp[n0 + wn * 64 + mi * 16 + quad * 4];
#pragma unroll
        for (int bi = 0; bi < 4; ++bi) {
          f32x4 z = acc[mi][bi];
          float gi = sigmoidf_(z[0] + bi4.x);
          float gf = sigmoidf_(z[1] + bi4.y);
          float gg = tanhf_(z[2] + bi4.z);
          float go = sigmoidf_(z[3] + bi4.w);
          const int ci = mi * 4 + bi;
          float cnew = gf * creg[ci] + gi * gg;
          float hnew = go * tanhf_(cnew);
          creg[ci] = cnew;
          hT[(wb * 64 + bi * 16 + lrow) * 68 + wn * 16 + mi * 4 + quad] = f2bf(hnew);
          if (t >= PREV) psum[bi] += hnew * w2r[mi];
          if (t == PREV - 1)
            cstore4(&cbuf[(size_t)(r0 + wb * 64 + bi * 16 + lrow) * HIDDEN
                          + nt * 64 + wn * 16 + mi * 4 + quad], cnew);
        }
      }
      if (t + 1 < TSTEPS) {
        // transpose hT -> bF[t+1] h-fragments (bg = r0/16 + 0..7, kg = nt*2 + 0..1),
        // 16 KB per block, coalesced LLC write-through stores.
        __syncthreads();
        char* bT1 = bF + (size_t)(t + 1) * STEPB;
#pragma unroll
        for (int pass = 0; pass < 2; ++pass) {
          int s = tid + pass * 512;
          int f = s >> 6, lq = s & 63;
          int bgl = f >> 1, kgl = f & 1;
          int br = bgl * 16 + (lq & 15);
          int jb = kgl * 32 + (lq >> 4) * 8;
          ull d0 = *(const ull*)&hT[br * 68 + jb];
          ull d1 = *(const ull*)&hT[br * 68 + jb + 4];
          char* dst = bT1 + (((size_t)((r0 >> 4) + bgl) * NKG + nt * 2 + kgl) << 10) + lq * 16;
          cstore(dst, d0);
          cstore(dst + 8, d1);
        }
      }
      if (t >= PREV) {
#pragma unroll
        for (int bi = 0; bi < 4; ++bi) {
          float v = psum[bi];
          v += __shfl_down(v, 32);
          v += __shfl_down(v, 16);
          if (quad == 0)
            atomicAdd(&accout[(size_t)(r0 + wb * 64 + bi * 16 + lrow) * PRED + kout], v);
        }
      }
    }

    // ---- grid barrier (LLC atomics). __syncthreads' vmcnt(0)/lgkmcnt(0) drain
    // puts the h-frag / cell stores at the LLC before the signal.
    if (t < TSTEPS - 1) {
      __syncthreads();
      if (tid == 0) {
        unsigned ph = (unsigned)(t + 1);
        unsigned old = __hip_atomic_fetch_add(cnt, 1u, __ATOMIC_RELAXED, __HIP_MEMORY_SCOPE_AGENT);
        if (old == NBLK - 1) {
          __hip_atomic_store(cnt, 0u, __ATOMIC_RELAXED, __HIP_MEMORY_SCOPE_AGENT);
          __hip_atomic_store(flag, ph, __ATOMIC_RELAXED, __HIP_MEMORY_SCOPE_AGENT);
        } else {
          while (__hip_atomic_load(flag, __ATOMIC_RELAXED, __HIP_MEMORY_SCOPE_AGENT) < ph)
            __builtin_amdgcn_s_sleep(4);
        }
      }
      __syncthreads();
    }
  }
#undef LOADA
#undef LOADB
#undef COMP
}

// ---- final tanh chain over the 40960 fused dots ----
__global__ void final_kernel(const float* __restrict__ accout, const float* __restrict__ b2,
                             const float* __restrict__ w3, const float* __restrict__ b3,
                             const float* __restrict__ w4, const float* __restrict__ b4,
                             float* __restrict__ out) {
  int i = blockIdx.x * 256 + threadIdx.x;
  const int half = BATCH * PRED;
  if (i >= 2 * half) return;
  int r, k;
  if (i < half) {
    r = i / PRED;
    k = i % PRED;
  } else {
    r = BATCH + (i - half) / PRED;
    k = (i - half) % PRED;
  }
  float x = tanhf_(accout[r * PRED + k] + b2[0]);
  x = tanhf_(x * w3[0] + b3[0]);
  x = tanhf_(x * w4[0] + b4[0]);
  out[i] = x;
}

extern "C" void kernel_launch(void* const* d_in, const int* in_sizes, int n_in,
                              void* d_out, int out_size, void* d_ws, size_t ws_size,
                              hipStream_t stream) {
  const float* real_input = (const float*)d_in[0];
  const float* fake_input = (const float*)d_in[1];
  const float* Wx = (const float*)d_in[2];
  const float* Wh = (const float*)d_in[3];
  const float* b  = (const float*)d_in[4];
  const float* w2 = (const float*)d_in[5];
  const float* b2 = (const float*)d_in[6];
  const float* w3 = (const float*)d_in[7];
  const float* b3 = (const float*)d_in[8];
  const float* w4 = (const float*)d_in[9];
  const float* b4 = (const float*)d_in[10];
  float* out = (float*)d_out;

  char* ws = (char*)d_ws;
  size_t off = 0;
  __hip_bfloat16* Wf = (__hip_bfloat16*)(ws + off);   off += (size_t)N4H * KTOT * 2;
  float* biasp = (float*)(ws + off);                  off += (size_t)N4H * 4;
  float* cbuf = (float*)(ws + off);                   off += (size_t)BATCH * HIDDEN * 4;
  float* accout = (float*)(ws + off);                 off += (size_t)2 * BATCH * PRED * 4;
  unsigned* bar = (unsigned*)(ws + off);              off += 1024;
  char* bF = ws + off;                                off += (size_t)TSTEPS * STEPB;
  // WpT (pack intermediate, 12 MB) aliases bF[t=28..29] (x-part written by
  // pack_bx AFTER pack_wf consumed WpT; h-part only written at runtime t=27/28)
  __hip_bfloat16* WpT = (__hip_bfloat16*)(bF + (size_t)28 * STEPB);

  hipMemsetAsync(bF, 0, STEPB, stream);  // bF[0] h-part = h_{-1} = 0
  hipMemsetAsync(accout, 0, (size_t)2 * BATCH * PRED * 4, stream);
  hipMemsetAsync(bar, 0, 1024, stream);

  pack_w_kernel<<<dim3(KTOT / 64, N4H / 64), 256, 0, stream>>>(Wx, Wh, WpT);
  pack_bias_kernel<<<N4H / 256, 256, 0, stream>>>(b, biasp);
  pack_wf_kernel<<<((N4H / 16) * NKG * 64 + 255) / 256, 256, 0, stream>>>(WpT, Wf);
  {
    int nthr = (64 * TSTEPS * 16 + 64 * PRED * 16) * 64;
    pack_bx_kernel<<<(nthr + 255) / 256, 256, 0, stream>>>(real_input, fake_input, bF);
  }

  {
    char* a_bF = bF;
    const __hip_bfloat16* a_Wf = Wf;
    const float* a_biasp = biasp;
    const float* a_w2 = w2;
    float* a_cbuf = cbuf;
    float* a_acc = accout;
    unsigned* a_bar = bar;
    void* args[7] = {&a_bF, &a_Wf, &a_biasp, &a_w2, &a_cbuf, &a_acc, &a_bar};
    hipError_t e = hipLaunchCooperativeKernel((const void*)lstm_persistent,
                                              dim3(NBLK), dim3(NTHR), args, 0, stream);
    if (e != hipSuccess) {
      // co-residency fallback: 256 blocks at 17 KB LDS are 1/CU resident
      lstm_persistent<<<dim3(NBLK), dim3(NTHR), 0, stream>>>(
          bF, Wf, biasp, w2, cbuf, accout, bar);
    }
  }

  final_kernel<<<(2 * BATCH * PRED + 255) / 256, 256, 0, stream>>>(accout, b2, w3, b3, w4, b4, out);
}